// Round 1
// baseline (682.772 us; speedup 1.0000x reference)
//
#include <hip/hip_runtime.h>
#include <hip/hip_bf16.h>

// bf16 bit helpers (exact upconvert; RNE downconvert via HIP API)
static __device__ __forceinline__ float bf2f(unsigned short u) {
    return __uint_as_float(((unsigned int)u) << 16);
}
static __device__ __forceinline__ unsigned short f2bf(float f) {
    __hip_bfloat16 b = __float2bfloat16(f);
    return *reinterpret_cast<unsigned short*>(&b);
}

// ---------------------------------------------------------------------------
// Precompute: Y[n][0:128]   = h[n] @ W1[0:128]     (src-part)
//             Y[n][128:256] = h[n] @ W1[128:256]   (dst-part)
// h: [n][128] fp32, W1: [272][128] fp32, Y: [n][256] bf16
// Tiling: 64 nodes x 256 cols per block (4 chunks of 64 cols), K=128 staged.
// ---------------------------------------------------------------------------
extern "C" __global__ __launch_bounds__(256)
void precompute_gemm(const float* __restrict__ h, int n,
                     const float* __restrict__ W1,
                     unsigned short* __restrict__ Y)
{
    __shared__ float As[128][68];   // [k][m], padded lead to dodge conflicts
    __shared__ float Bs[128][68];   // [k][jj]
    const int tid = threadIdx.x;
    const int node0 = blockIdx.x * 64;

    // stage A transposed: As[k][m] = h[node0+m][k]
    for (int i = tid; i < 64 * 128; i += 256) {
        int m = i >> 7, k = i & 127;
        int row = node0 + m;
        As[k][m] = (row < n) ? h[(size_t)row * 128 + k] : 0.0f;
    }

    const int tr = tid >> 4, tc = tid & 15;

    for (int c = 0; c < 4; ++c) {
        const int j0 = c * 64;
        __syncthreads();  // prev-iter readers done before Bs overwrite (also A ready)
        for (int i = tid; i < 128 * 64; i += 256) {
            int k = i >> 6, jj = i & 63;
            int j = j0 + jj;
            Bs[k][jj] = (j < 128) ? W1[k * 128 + j]
                                  : W1[(128 + k) * 128 + (j - 128)];
        }
        __syncthreads();

        float acc[4][4] = {};
        #pragma unroll 8
        for (int k = 0; k < 128; ++k) {
            float4 a4 = *(const float4*)&As[k][tr * 4];
            float4 b4 = *(const float4*)&Bs[k][tc * 4];
            float av[4] = {a4.x, a4.y, a4.z, a4.w};
            float bv[4] = {b4.x, b4.y, b4.z, b4.w};
            #pragma unroll
            for (int i = 0; i < 4; ++i)
                #pragma unroll
                for (int j = 0; j < 4; ++j)
                    acc[i][j] = fmaf(av[i], bv[j], acc[i][j]);
        }

        #pragma unroll
        for (int i = 0; i < 4; ++i) {
            int m = node0 + tr * 4 + i;
            if (m < n) {
                ushort4 u;
                u.x = f2bf(acc[i][0]); u.y = f2bf(acc[i][1]);
                u.z = f2bf(acc[i][2]); u.w = f2bf(acc[i][3]);
                *(ushort4*)&Y[(size_t)m * 256 + j0 + tc * 4] = u;
            }
        }
    }
}

// ---------------------------------------------------------------------------
// Edge phase (precomputed path): one wave per edge.
// Lane l owns h1 features {2l, 2l+1} and h2 output (l&31) (paired across halves).
// W1c (16x128) and W2 (128x32) live in per-lane registers; h1 goes through a
// per-wave LDS buffer (wave-synchronous, DS ops are in-order per wave).
// ---------------------------------------------------------------------------
extern "C" __global__ __launch_bounds__(256)
void edge_mlp_pre(const unsigned short* __restrict__ Yu,
                  const unsigned short* __restrict__ Yi,
                  const float* __restrict__ ef_orders,
                  const float* __restrict__ ef_rev,
                  const int* __restrict__ src_orders,
                  const int* __restrict__ dst_orders,
                  const int* __restrict__ src_rev,
                  const int* __restrict__ dst_rev,
                  const float* __restrict__ W1,
                  const float* __restrict__ b1,
                  const float* __restrict__ W2,
                  const float* __restrict__ b2,
                  const float* __restrict__ W3,
                  const float* __restrict__ b3,
                  float* __restrict__ out, int E)
{
    __shared__ float h1s[4][128];
    const int tid = threadIdx.x;
    const int wave = tid >> 6, lane = tid & 63;
    const int f0 = 2 * lane;
    const int j2 = lane & 31;
    const int kb = (lane >> 5) * 64;

    // lane-resident weights (all statically indexed -> registers)
    float w1c0[16], w1c1[16];
    #pragma unroll
    for (int k = 0; k < 16; ++k) {
        w1c0[k] = W1[(256 + k) * 128 + f0];
        w1c1[k] = W1[(256 + k) * 128 + f0 + 1];
    }
    float w2r[64];
    #pragma unroll
    for (int kk = 0; kk < 64; ++kk)
        w2r[kk] = W2[(kb + kk) * 32 + j2];
    const float b10 = b1[f0], b11 = b1[f0 + 1];
    const float b2v = b2[j2], w3v = W3[j2], b3v = b3[0];

    const long twoE = 2L * E;
    for (long e = (long)blockIdx.x * 4 + wave; e < twoE; e += (long)gridDim.x * 4) {
        const bool rv = (e >= E);
        const int ee = (int)(rv ? e - E : e);
        const int s = (rv ? src_rev : src_orders)[ee];
        const int d = (rv ? dst_rev : dst_orders)[ee];
        const unsigned short* Ys = rv ? Yi : Yu;
        const unsigned short* Yd = rv ? Yu : Yi;
        const float* efp = rv ? ef_rev : ef_orders;

        // gather precomputed partials (bf16, coalesced ushort2 per lane)
        ushort2 us = *(const ushort2*)&Ys[(size_t)s * 256 + f0];
        ushort2 ud = *(const ushort2*)&Yd[(size_t)d * 256 + 128 + f0];
        float p0 = bf2f(us.x) + bf2f(ud.x) + b10;
        float p1 = bf2f(us.y) + bf2f(ud.y) + b11;

        // + ef @ W1c  (ef broadcast via shfl, W1c in registers)
        const float efv = efp[(size_t)ee * 16 + (lane & 15)];
        #pragma unroll
        for (int k = 0; k < 16; ++k) {
            float ek = __shfl(efv, k, 64);
            p0 = fmaf(ek, w1c0[k], p0);
            p1 = fmaf(ek, w1c1[k], p1);
        }
        p0 = fmaxf(p0, 0.0f);
        p1 = fmaxf(p1, 0.0f);

        // publish h1 to the wave
        *(float2*)&h1s[wave][f0] = make_float2(p0, p1);
        __builtin_amdgcn_wave_barrier();

        // h2[j2] partial over 64 k's (other half via shfl_xor 32)
        float acc = 0.0f;
        #pragma unroll
        for (int q = 0; q < 16; ++q) {
            float4 hv = *(const float4*)&h1s[wave][kb + q * 4];
            acc = fmaf(hv.x, w2r[4 * q + 0], acc);
            acc = fmaf(hv.y, w2r[4 * q + 1], acc);
            acc = fmaf(hv.z, w2r[4 * q + 2], acc);
            acc = fmaf(hv.w, w2r[4 * q + 3], acc);
        }
        __builtin_amdgcn_wave_barrier();
        acc += __shfl_xor(acc, 32, 64);
        float h2 = fmaxf(acc + b2v, 0.0f);

        // out = sigmoid(h2 . W3 + b3), reduce 32 lanes
        float v = h2 * w3v;
        v += __shfl_xor(v, 16, 64);
        v += __shfl_xor(v, 8, 64);
        v += __shfl_xor(v, 4, 64);
        v += __shfl_xor(v, 2, 64);
        v += __shfl_xor(v, 1, 64);
        if (lane == 0)
            out[e] = 1.0f / (1.0f + __expf(-(v + b3v)));
    }
}

// ---------------------------------------------------------------------------
// Fallback (if ws too small): direct per-edge MLP, W1[0:256] staged bf16 in LDS.
// ---------------------------------------------------------------------------
extern "C" __global__ __launch_bounds__(256)
void edge_mlp_direct(const float* __restrict__ h_user,
                     const float* __restrict__ h_item,
                     const float* __restrict__ ef_orders,
                     const float* __restrict__ ef_rev,
                     const int* __restrict__ src_orders,
                     const int* __restrict__ dst_orders,
                     const int* __restrict__ src_rev,
                     const int* __restrict__ dst_rev,
                     const float* __restrict__ W1,
                     const float* __restrict__ b1,
                     const float* __restrict__ W2,
                     const float* __restrict__ b2,
                     const float* __restrict__ W3,
                     const float* __restrict__ b3,
                     float* __restrict__ out, int E)
{
    __shared__ unsigned short W1s[256][128];  // bf16 W1 rows 0..255
    __shared__ float xbuf[4][256];
    __shared__ float h1s[4][128];
    const int tid = threadIdx.x;
    const int wave = tid >> 6, lane = tid & 63;
    const int f0 = 2 * lane;
    const int j2 = lane & 31;
    const int kb = (lane >> 5) * 64;

    for (int i = tid; i < 256 * 128; i += 256)
        W1s[i >> 7][i & 127] = f2bf(W1[i]);
    __syncthreads();

    float w1c0[16], w1c1[16];
    #pragma unroll
    for (int k = 0; k < 16; ++k) {
        w1c0[k] = W1[(256 + k) * 128 + f0];
        w1c1[k] = W1[(256 + k) * 128 + f0 + 1];
    }
    float w2r[64];
    #pragma unroll
    for (int kk = 0; kk < 64; ++kk)
        w2r[kk] = W2[(kb + kk) * 32 + j2];
    const float b10 = b1[f0], b11 = b1[f0 + 1];
    const float b2v = b2[j2], w3v = W3[j2], b3v = b3[0];

    const long twoE = 2L * E;
    for (long e = (long)blockIdx.x * 4 + wave; e < twoE; e += (long)gridDim.x * 4) {
        const bool rv = (e >= E);
        const int ee = (int)(rv ? e - E : e);
        const int s = (rv ? src_rev : src_orders)[ee];
        const int d = (rv ? dst_rev : dst_orders)[ee];
        const float* hs = rv ? h_item : h_user;
        const float* hd = rv ? h_user : h_item;
        const float* efp = rv ? ef_rev : ef_orders;

        xbuf[wave][lane]       = hs[(size_t)s * 128 + lane];
        xbuf[wave][64 + lane]  = hs[(size_t)s * 128 + 64 + lane];
        xbuf[wave][128 + lane] = hd[(size_t)d * 128 + lane];
        xbuf[wave][192 + lane] = hd[(size_t)d * 128 + 64 + lane];
        __builtin_amdgcn_wave_barrier();

        float p0 = b10, p1 = b11;
        #pragma unroll 8
        for (int k = 0; k < 256; ++k) {
            float xv = xbuf[wave][k];
            ushort2 w = *(const ushort2*)&W1s[k][f0];
            p0 = fmaf(xv, bf2f(w.x), p0);
            p1 = fmaf(xv, bf2f(w.y), p1);
        }
        const float efv = efp[(size_t)ee * 16 + (lane & 15)];
        #pragma unroll
        for (int k = 0; k < 16; ++k) {
            float ek = __shfl(efv, k, 64);
            p0 = fmaf(ek, w1c0[k], p0);
            p1 = fmaf(ek, w1c1[k], p1);
        }
        p0 = fmaxf(p0, 0.0f);
        p1 = fmaxf(p1, 0.0f);

        *(float2*)&h1s[wave][f0] = make_float2(p0, p1);
        __builtin_amdgcn_wave_barrier();
        float acc = 0.0f;
        #pragma unroll
        for (int q = 0; q < 16; ++q) {
            float4 hv = *(const float4*)&h1s[wave][kb + q * 4];
            acc = fmaf(hv.x, w2r[4 * q + 0], acc);
            acc = fmaf(hv.y, w2r[4 * q + 1], acc);
            acc = fmaf(hv.z, w2r[4 * q + 2], acc);
            acc = fmaf(hv.w, w2r[4 * q + 3], acc);
        }
        __builtin_amdgcn_wave_barrier();
        acc += __shfl_xor(acc, 32, 64);
        float h2 = fmaxf(acc + b2v, 0.0f);
        float v = h2 * w3v;
        v += __shfl_xor(v, 16, 64);
        v += __shfl_xor(v, 8, 64);
        v += __shfl_xor(v, 4, 64);
        v += __shfl_xor(v, 2, 64);
        v += __shfl_xor(v, 1, 64);
        if (lane == 0)
            out[e] = 1.0f / (1.0f + __expf(-(v + b3v)));
    }
}

// ---------------------------------------------------------------------------
extern "C" void kernel_launch(void* const* d_in, const int* in_sizes, int n_in,
                              void* d_out, int out_size, void* d_ws, size_t ws_size,
                              hipStream_t stream)
{
    const float* h_user    = (const float*)d_in[0];
    const float* h_item    = (const float*)d_in[1];
    const float* ef_orders = (const float*)d_in[2];
    const float* ef_rev    = (const float*)d_in[3];
    const float* W1        = (const float*)d_in[4];
    const float* b1        = (const float*)d_in[5];
    const float* W2        = (const float*)d_in[6];
    const float* b2        = (const float*)d_in[7];
    const float* W3        = (const float*)d_in[8];
    const float* b3        = (const float*)d_in[9];
    const int* src_orders  = (const int*)d_in[10];
    const int* dst_orders  = (const int*)d_in[11];
    const int* src_rev     = (const int*)d_in[12];
    const int* dst_rev     = (const int*)d_in[13];

    const int n_user = in_sizes[0] / 128;
    const int n_item = in_sizes[1] / 128;
    const int E      = in_sizes[2] / 16;
    float* out = (float*)d_out;

    const size_t need = (size_t)(n_user + n_item) * 256 * sizeof(unsigned short);
    if (ws_size >= need) {
        unsigned short* Yu = (unsigned short*)d_ws;
        unsigned short* Yi = Yu + (size_t)n_user * 256;
        precompute_gemm<<<(n_user + 63) / 64, 256, 0, stream>>>(h_user, n_user, W1, Yu);
        precompute_gemm<<<(n_item + 63) / 64, 256, 0, stream>>>(h_item, n_item, W1, Yi);
        edge_mlp_pre<<<4096, 256, 0, stream>>>(Yu, Yi, ef_orders, ef_rev,
            src_orders, dst_orders, src_rev, dst_rev,
            W1, b1, W2, b2, W3, b3, out, E);
    } else {
        edge_mlp_direct<<<4096, 256, 0, stream>>>(h_user, h_item, ef_orders, ef_rev,
            src_orders, dst_orders, src_rev, dst_rev,
            W1, b1, W2, b2, W3, b3, out, E);
    }
}

// Round 2
// 260.779 us; speedup vs baseline: 2.6182x; 2.6182x over previous
//
#include <hip/hip_runtime.h>
#include <hip/hip_bf16.h>

typedef __attribute__((ext_vector_type(8))) short bfrag;   // 8 bf16 (A/B operand)
typedef __attribute__((ext_vector_type(4))) float facc;    // 4 f32  (C/D operand)

static __device__ __forceinline__ float bf2f_lo(unsigned int u) {
    return __uint_as_float(u << 16);
}
static __device__ __forceinline__ float bf2f_hi(unsigned int u) {
    return __uint_as_float(u & 0xffff0000u);
}
static __device__ __forceinline__ short f2bf(float f) {
    __hip_bfloat16 b = __float2bfloat16(f);  // RNE
    return *reinterpret_cast<short*>(&b);
}

// ---------------------------------------------------------------------------
// Precompute: Y[row][0:128] = h[row] @ W1[0:128], Y[row][128:256] = h[row] @ W1[128:256]
// MFMA 16x16x32 bf16. Block = 4 waves; wave w owns cols [w*64, w*64+64).
// B (W1) fragments loop-invariant in registers; A (h rows) loaded f32 -> bf16.
// D layout (verified): col = lane&15, row = (lane>>4)*4 + reg.
// ---------------------------------------------------------------------------
extern "C" __global__ __launch_bounds__(256)
void precompute_mfma(const float* __restrict__ h, int n,
                     const float* __restrict__ W1,
                     unsigned short* __restrict__ Y)
{
    const int tid = threadIdx.x, wave = tid >> 6, lane = tid & 63;
    const int g = lane >> 4, e16 = lane & 15;
    const int c0 = wave * 64;

    // B frags: bfr[nt][kk], element i <-> k = kk*32 + g*8 + i, col j = c0 + nt*16 + e16
    bfrag bfr[4][4];
    #pragma unroll
    for (int nt = 0; nt < 4; ++nt) {
        const int j = c0 + nt * 16 + e16;
        #pragma unroll
        for (int kk = 0; kk < 4; ++kk) {
            bfrag v;
            #pragma unroll
            for (int i = 0; i < 8; ++i) {
                int k = kk * 32 + g * 8 + i;
                float w = (j < 128) ? W1[(size_t)k * 128 + j]
                                    : W1[(size_t)(128 + k) * 128 + (j - 128)];
                v[i] = f2bf(w);
            }
            bfr[nt][kk] = v;
        }
    }

    const int ntiles = (n + 15) >> 4;
    for (int tile = blockIdx.x; tile < ntiles; tile += gridDim.x) {
        const int node0 = tile * 16;
        int arow = node0 + e16; if (arow >= n) arow = n - 1;
        facc acc[4] = {{0,0,0,0},{0,0,0,0},{0,0,0,0},{0,0,0,0}};
        #pragma unroll
        for (int kk = 0; kk < 4; ++kk) {
            const float* ap = h + (size_t)arow * 128 + kk * 32 + g * 8;
            float4 a0 = *(const float4*)ap;
            float4 a1 = *(const float4*)(ap + 4);
            bfrag af;
            af[0] = f2bf(a0.x); af[1] = f2bf(a0.y); af[2] = f2bf(a0.z); af[3] = f2bf(a0.w);
            af[4] = f2bf(a1.x); af[5] = f2bf(a1.y); af[6] = f2bf(a1.z); af[7] = f2bf(a1.w);
            #pragma unroll
            for (int nt = 0; nt < 4; ++nt)
                acc[nt] = __builtin_amdgcn_mfma_f32_16x16x32_bf16(af, bfr[nt][kk], acc[nt], 0, 0, 0);
        }
        #pragma unroll
        for (int nt = 0; nt < 4; ++nt)
            #pragma unroll
            for (int r = 0; r < 4; ++r) {
                int row = node0 + g * 4 + r;
                if (row < n)
                    Y[(size_t)row * 256 + c0 + nt * 16 + e16] = (unsigned short)f2bf(acc[nt][r]);
            }
    }
}

// ---------------------------------------------------------------------------
// Edge phase: 16 edges per wave per iteration, edges-as-columns MFMA.
//  D1[n][e] = W1c^T @ ef^T (+b1 via C)  -> LDS (XOR-swizzled) -> transpose
//  P[e][k]  = relu(Ys[s_e][k] + Yd[d_e][128+k] + D1[k][e])    -> bf16 frags
//  D2[n][e] = W2^T @ P^T  -> tail 32->1 in-register, 2 shfl_xor, sigmoid.
// All loop-invariant weights live in per-lane registers as MFMA fragments.
// Per-wave private LDS buffer; wave-order DS semantics -> no barriers in loop.
// ---------------------------------------------------------------------------
extern "C" __global__ __launch_bounds__(256)
void edge_mfma(const unsigned short* __restrict__ Yu,
               const unsigned short* __restrict__ Yi,
               const float* __restrict__ ef_orders,
               const float* __restrict__ ef_rev,
               const int* __restrict__ src_orders,
               const int* __restrict__ dst_orders,
               const int* __restrict__ src_rev,
               const int* __restrict__ dst_rev,
               const float* __restrict__ W1,
               const float* __restrict__ b1,
               const float* __restrict__ W2,
               const float* __restrict__ b2,
               const float* __restrict__ W3,
               const float* __restrict__ b3,
               float* __restrict__ out, int E)
{
    __shared__ __align__(16) float efw_lds[4][16][128];
    const int tid = threadIdx.x, wave = tid >> 6, lane = tid & 63;
    const int g = lane >> 4, e16 = lane & 15;
    float (*my_lds)[128] = efw_lds[wave];
    const int swz = (e16 & 7) << 2;   // XOR on dword bits 2..4 -> 8 distinct 16B slots

    // A frags for ef GEMM: a1[t] = W1c^T tile t; slots with k>=16 are zero
    bfrag a1[8];
    #pragma unroll
    for (int t = 0; t < 8; ++t) {
        bfrag v;
        #pragma unroll
        for (int i = 0; i < 8; ++i) {
            int k = g * 8 + i;
            v[i] = (k < 16) ? f2bf(W1[(size_t)(256 + k) * 128 + t * 16 + e16]) : (short)0;
        }
        a1[t] = v;
    }
    // C-init with b1 (row = g*4 + r in D layout)
    facc cb1[8];
    #pragma unroll
    for (int t = 0; t < 8; ++t)
        #pragma unroll
        for (int r = 0; r < 4; ++r)
            cb1[t][r] = b1[t * 16 + g * 4 + r];
    // W2^T A-frags for the second GEMM
    bfrag w2t[2][4];
    #pragma unroll
    for (int nt = 0; nt < 2; ++nt)
        #pragma unroll
        for (int kk = 0; kk < 4; ++kk) {
            bfrag v;
            #pragma unroll
            for (int i = 0; i < 8; ++i) {
                int k = kk * 32 + g * 8 + i;
                v[i] = f2bf(W2[(size_t)k * 32 + nt * 16 + e16]);
            }
            w2t[nt][kk] = v;
        }
    float b2v[2][4], w3v[2][4];
    #pragma unroll
    for (int nt = 0; nt < 2; ++nt)
        #pragma unroll
        for (int r = 0; r < 4; ++r) {
            b2v[nt][r] = b2[nt * 16 + g * 4 + r];
            w3v[nt][r] = W3[nt * 16 + g * 4 + r];
        }
    const float b3s = b3[0];

    const long twoE = 2L * E;
    const int nbatch = (int)((twoE + 15) >> 4);
    const int gw = gridDim.x * 4;

    for (int b = blockIdx.x * 4 + wave; b < nbatch; b += gw) {
        const long el = ((long)b << 4) + e16;       // this lane's edge (as column)
        const bool valid = el < twoE;
        const bool rv = el >= E;
        const int ee = valid ? (int)(rv ? el - E : el) : 0;
        const int s = (rv ? src_rev : src_orders)[ee];
        const int d = (rv ? dst_rev : dst_orders)[ee];
        const unsigned short* Ys = rv ? Yi : Yu;
        const unsigned short* Yd = rv ? Yu : Yi;
        const float* efp = rv ? ef_rev : ef_orders;

        // B frag: ef^T, slots k>=16 zero (lanes g>=2)
        bfrag eb = {0, 0, 0, 0, 0, 0, 0, 0};
        if (g < 2) {
            const float* ep = efp + (size_t)ee * 16 + g * 8;
            float4 x0 = *(const float4*)ep;
            float4 x1 = *(const float4*)(ep + 4);
            eb[0] = f2bf(x0.x); eb[1] = f2bf(x0.y); eb[2] = f2bf(x0.z); eb[3] = f2bf(x0.w);
            eb[4] = f2bf(x1.x); eb[5] = f2bf(x1.y); eb[6] = f2bf(x1.z); eb[7] = f2bf(x1.w);
        }

        // D1 = W1c^T @ ef^T + b1  -> LDS transpose (swizzled)
        #pragma unroll
        for (int t = 0; t < 8; ++t) {
            facc d1 = __builtin_amdgcn_mfma_f32_16x16x32_bf16(a1[t], eb, cb1[t], 0, 0, 0);
            *(facc*)&my_lds[e16][(t * 16 + g * 4) ^ swz] = d1;
        }

        // P build + second GEMM, K-step by K-step
        facc acc2[2] = {{0,0,0,0},{0,0,0,0}};
        #pragma unroll
        for (int kk = 0; kk < 4; ++kk) {
            const int k0 = kk * 32 + g * 8;
            uint4 ysu = *(const uint4*)(Ys + (size_t)s * 256 + k0);
            uint4 ydu = *(const uint4*)(Yd + (size_t)d * 256 + 128 + k0);
            float4 w0 = *(const float4*)&my_lds[e16][k0 ^ swz];
            float4 w1 = *(const float4*)&my_lds[e16][(k0 + 4) ^ swz];
            float p0 = bf2f_lo(ysu.x) + bf2f_lo(ydu.x) + w0.x;
            float p1 = bf2f_hi(ysu.x) + bf2f_hi(ydu.x) + w0.y;
            float p2 = bf2f_lo(ysu.y) + bf2f_lo(ydu.y) + w0.z;
            float p3 = bf2f_hi(ysu.y) + bf2f_hi(ydu.y) + w0.w;
            float p4 = bf2f_lo(ysu.z) + bf2f_lo(ydu.z) + w1.x;
            float p5 = bf2f_hi(ysu.z) + bf2f_hi(ydu.z) + w1.y;
            float p6 = bf2f_lo(ysu.w) + bf2f_lo(ydu.w) + w1.z;
            float p7 = bf2f_hi(ysu.w) + bf2f_hi(ydu.w) + w1.w;
            bfrag pa;
            pa[0] = f2bf(fmaxf(p0, 0.f)); pa[1] = f2bf(fmaxf(p1, 0.f));
            pa[2] = f2bf(fmaxf(p2, 0.f)); pa[3] = f2bf(fmaxf(p3, 0.f));
            pa[4] = f2bf(fmaxf(p4, 0.f)); pa[5] = f2bf(fmaxf(p5, 0.f));
            pa[6] = f2bf(fmaxf(p6, 0.f)); pa[7] = f2bf(fmaxf(p7, 0.f));
            acc2[0] = __builtin_amdgcn_mfma_f32_16x16x32_bf16(w2t[0][kk], pa, acc2[0], 0, 0, 0);
            acc2[1] = __builtin_amdgcn_mfma_f32_16x16x32_bf16(w2t[1][kk], pa, acc2[1], 0, 0, 0);
        }

        // tail: relu(h2+b2) . W3, reduce over g-groups, sigmoid
        float h3 = 0.f;
        #pragma unroll
        for (int nt = 0; nt < 2; ++nt)
            #pragma unroll
            for (int r = 0; r < 4; ++r) {
                float h2 = fmaxf(acc2[nt][r] + b2v[nt][r], 0.f);
                h3 = fmaf(h2, w3v[nt][r], h3);
            }
        h3 += __shfl_xor(h3, 16, 64);
        h3 += __shfl_xor(h3, 32, 64);
        if (lane < 16 && valid)
            out[el] = 1.f / (1.f + __expf(-(h3 + b3s)));
    }
}

// ---------------------------------------------------------------------------
// Fallback (ws too small): direct per-edge MLP (round-1 kernel, known good).
// ---------------------------------------------------------------------------
extern "C" __global__ __launch_bounds__(256)
void edge_mlp_direct(const float* __restrict__ h_user,
                     const float* __restrict__ h_item,
                     const float* __restrict__ ef_orders,
                     const float* __restrict__ ef_rev,
                     const int* __restrict__ src_orders,
                     const int* __restrict__ dst_orders,
                     const int* __restrict__ src_rev,
                     const int* __restrict__ dst_rev,
                     const float* __restrict__ W1,
                     const float* __restrict__ b1,
                     const float* __restrict__ W2,
                     const float* __restrict__ b2,
                     const float* __restrict__ W3,
                     const float* __restrict__ b3,
                     float* __restrict__ out, int E)
{
    __shared__ unsigned short W1s[256][128];
    __shared__ float xbuf[4][256];
    __shared__ float h1s[4][128];
    const int tid = threadIdx.x;
    const int wave = tid >> 6, lane = tid & 63;
    const int f0 = 2 * lane;
    const int j2 = lane & 31;
    const int kb = (lane >> 5) * 64;

    for (int i = tid; i < 256 * 128; i += 256)
        W1s[i >> 7][i & 127] = (unsigned short)f2bf(W1[i]);
    __syncthreads();

    float w1c0[16], w1c1[16];
    #pragma unroll
    for (int k = 0; k < 16; ++k) {
        w1c0[k] = W1[(256 + k) * 128 + f0];
        w1c1[k] = W1[(256 + k) * 128 + f0 + 1];
    }
    float w2r[64];
    #pragma unroll
    for (int kk = 0; kk < 64; ++kk)
        w2r[kk] = W2[(kb + kk) * 32 + j2];
    const float b10 = b1[f0], b11 = b1[f0 + 1];
    const float b2vv = b2[j2], w3vv = W3[j2], b3v = b3[0];

    const long twoE = 2L * E;
    for (long e = (long)blockIdx.x * 4 + wave; e < twoE; e += (long)gridDim.x * 4) {
        const bool rv = (e >= E);
        const int ee = (int)(rv ? e - E : e);
        const int s = (rv ? src_rev : src_orders)[ee];
        const int d = (rv ? dst_rev : dst_orders)[ee];
        const float* hs = rv ? h_item : h_user;
        const float* hd = rv ? h_user : h_item;
        const float* efp = rv ? ef_rev : ef_orders;

        xbuf[wave][lane]       = hs[(size_t)s * 128 + lane];
        xbuf[wave][64 + lane]  = hs[(size_t)s * 128 + 64 + lane];
        xbuf[wave][128 + lane] = hd[(size_t)d * 128 + lane];
        xbuf[wave][192 + lane] = hd[(size_t)d * 128 + 64 + lane];
        __builtin_amdgcn_wave_barrier();

        float p0 = b10, p1 = b11;
        #pragma unroll 8
        for (int k = 0; k < 256; ++k) {
            float xv = xbuf[wave][k];
            unsigned int w = *(const unsigned int*)&W1s[k][f0];
            p0 = fmaf(xv, bf2f_lo(w), p0);
            p1 = fmaf(xv, bf2f_hi(w), p1);
        }
        const float efv = efp[(size_t)ee * 16 + (lane & 15)];
        #pragma unroll
        for (int k = 0; k < 16; ++k) {
            float ek = __shfl(efv, k, 64);
            p0 = fmaf(ek, w1c0[k], p0);
            p1 = fmaf(ek, w1c1[k], p1);
        }
        p0 = fmaxf(p0, 0.0f);
        p1 = fmaxf(p1, 0.0f);

        *(float2*)&h1s[wave][f0] = make_float2(p0, p1);
        __builtin_amdgcn_wave_barrier();
        float acc = 0.0f;
        #pragma unroll
        for (int q = 0; q < 16; ++q) {
            float4 hv = *(const float4*)&h1s[wave][kb + q * 4];
            acc = fmaf(hv.x, w2r[4 * q + 0], acc);
            acc = fmaf(hv.y, w2r[4 * q + 1], acc);
            acc = fmaf(hv.z, w2r[4 * q + 2], acc);
            acc = fmaf(hv.w, w2r[4 * q + 3], acc);
        }
        __builtin_amdgcn_wave_barrier();
        acc += __shfl_xor(acc, 32, 64);
        float h2 = fmaxf(acc + b2vv, 0.0f);
        float v = h2 * w3vv;
        v += __shfl_xor(v, 16, 64);
        v += __shfl_xor(v, 8, 64);
        v += __shfl_xor(v, 4, 64);
        v += __shfl_xor(v, 2, 64);
        v += __shfl_xor(v, 1, 64);
        if (lane == 0)
            out[e] = 1.0f / (1.0f + __expf(-(v + b3v)));
    }
}

// ---------------------------------------------------------------------------
extern "C" void kernel_launch(void* const* d_in, const int* in_sizes, int n_in,
                              void* d_out, int out_size, void* d_ws, size_t ws_size,
                              hipStream_t stream)
{
    const float* h_user    = (const float*)d_in[0];
    const float* h_item    = (const float*)d_in[1];
    const float* ef_orders = (const float*)d_in[2];
    const float* ef_rev    = (const float*)d_in[3];
    const float* W1        = (const float*)d_in[4];
    const float* b1        = (const float*)d_in[5];
    const float* W2        = (const float*)d_in[6];
    const float* b2        = (const float*)d_in[7];
    const float* W3        = (const float*)d_in[8];
    const float* b3        = (const float*)d_in[9];
    const int* src_orders  = (const int*)d_in[10];
    const int* dst_orders  = (const int*)d_in[11];
    const int* src_rev     = (const int*)d_in[12];
    const int* dst_rev     = (const int*)d_in[13];

    const int n_user = in_sizes[0] / 128;
    const int n_item = in_sizes[1] / 128;
    const int E      = in_sizes[2] / 16;
    float* out = (float*)d_out;

    const size_t need = (size_t)(n_user + n_item) * 256 * sizeof(unsigned short);
    if (ws_size >= need) {
        unsigned short* Yu = (unsigned short*)d_ws;
        unsigned short* Yi = Yu + (size_t)n_user * 256;
        precompute_mfma<<<1024, 256, 0, stream>>>(h_user, n_user, W1, Yu);
        precompute_mfma<<<1024, 256, 0, stream>>>(h_item, n_item, W1, Yi);
        edge_mfma<<<4096, 256, 0, stream>>>(Yu, Yi, ef_orders, ef_rev,
            src_orders, dst_orders, src_rev, dst_rev,
            W1, b1, W2, b2, W3, b3, out, E);
    } else {
        edge_mlp_direct<<<4096, 256, 0, stream>>>(h_user, h_item, ef_orders, ef_rev,
            src_orders, dst_orders, src_rev, dst_rev,
            W1, b1, W2, b2, W3, b3, out, E);
    }
}

// Round 3
// 248.144 us; speedup vs baseline: 2.7515x; 1.0509x over previous
//
#include <hip/hip_runtime.h>
#include <hip/hip_bf16.h>

typedef __attribute__((ext_vector_type(8))) short bfrag;   // 8 bf16 (A/B operand)
typedef __attribute__((ext_vector_type(4))) float facc;    // 4 f32  (C/D operand)

static __device__ __forceinline__ float bf2f_lo(unsigned int u) {
    return __uint_as_float(u << 16);
}
static __device__ __forceinline__ float bf2f_hi(unsigned int u) {
    return __uint_as_float(u & 0xffff0000u);
}
static __device__ __forceinline__ short f2bf(float f) {
    __hip_bfloat16 b = __float2bfloat16(f);  // RNE
    return *reinterpret_cast<short*>(&b);
}

// ---------------------------------------------------------------------------
// Merged precompute: Y[row][0:128] = h@W1[0:128], Y[row][128:256] = h@W1[128:256]
// for BOTH node tables in one launch (grid-stride over user tiles then item).
// MFMA 16x16x32 bf16; wave w owns cols [w*64, w*64+64); W1 frags in registers.
// D layout (verified): col = lane&15, row = (lane>>4)*4 + reg.
// ---------------------------------------------------------------------------
extern "C" __global__ __launch_bounds__(256)
void precompute_mfma(const float* __restrict__ hu, int nu,
                     const float* __restrict__ hi, int ni,
                     const float* __restrict__ W1,
                     unsigned short* __restrict__ Yu,
                     unsigned short* __restrict__ Yi)
{
    const int tid = threadIdx.x, wave = tid >> 6, lane = tid & 63;
    const int g = lane >> 4, e16 = lane & 15;
    const int c0 = wave * 64;

    bfrag bfr[4][4];
    #pragma unroll
    for (int nt = 0; nt < 4; ++nt) {
        const int j = c0 + nt * 16 + e16;
        #pragma unroll
        for (int kk = 0; kk < 4; ++kk) {
            bfrag v;
            #pragma unroll
            for (int i = 0; i < 8; ++i) {
                int k = kk * 32 + g * 8 + i;
                float w = (j < 128) ? W1[(size_t)k * 128 + j]
                                    : W1[(size_t)(128 + k) * 128 + (j - 128)];
                v[i] = f2bf(w);
            }
            bfr[nt][kk] = v;
        }
    }

    const int tu = (nu + 15) >> 4, ti = (ni + 15) >> 4, tt = tu + ti;
    for (int tile = blockIdx.x; tile < tt; tile += gridDim.x) {
        const float* h; unsigned short* Y; int n, node0;
        if (tile < tu) { h = hu; Y = Yu; n = nu; node0 = tile * 16; }
        else           { h = hi; Y = Yi; n = ni; node0 = (tile - tu) * 16; }

        int arow = node0 + e16; if (arow >= n) arow = n - 1;
        facc acc[4] = {{0,0,0,0},{0,0,0,0},{0,0,0,0},{0,0,0,0}};
        #pragma unroll
        for (int kk = 0; kk < 4; ++kk) {
            const float* ap = h + (size_t)arow * 128 + kk * 32 + g * 8;
            float4 a0 = *(const float4*)ap;
            float4 a1v = *(const float4*)(ap + 4);
            bfrag af;
            af[0] = f2bf(a0.x);  af[1] = f2bf(a0.y);  af[2] = f2bf(a0.z);  af[3] = f2bf(a0.w);
            af[4] = f2bf(a1v.x); af[5] = f2bf(a1v.y); af[6] = f2bf(a1v.z); af[7] = f2bf(a1v.w);
            #pragma unroll
            for (int nt = 0; nt < 4; ++nt)
                acc[nt] = __builtin_amdgcn_mfma_f32_16x16x32_bf16(af, bfr[nt][kk], acc[nt], 0, 0, 0);
        }
        #pragma unroll
        for (int nt = 0; nt < 4; ++nt)
            #pragma unroll
            for (int r = 0; r < 4; ++r) {
                int row = node0 + g * 4 + r;
                if (row < n)
                    Y[(size_t)row * 256 + c0 + nt * 16 + e16] = (unsigned short)f2bf(acc[nt][r]);
            }
    }
}

// ---------------------------------------------------------------------------
// Edge phase: 16 edges/wave/iter, edges-as-columns MFMA, software-pipelined:
//   - Y/ef gathers for batch b+1 issued right after batch b's Y regs are
//     consumed (raw loads only; conversions deferred to the consuming iter)
//   - indices loaded 2 iterations ahead
//   - b1 folded into the ef-GEMM via a K=16 bias slot (A[n][16]=b1[n], B=1)
// Per-wave private LDS transpose buffer; no barriers in the loop.
// ---------------------------------------------------------------------------
extern "C" __global__ __launch_bounds__(256, 3)
void edge_mfma(const unsigned short* __restrict__ Yu,
               const unsigned short* __restrict__ Yi,
               const float* __restrict__ ef_orders,
               const float* __restrict__ ef_rev,
               const int* __restrict__ src_orders,
               const int* __restrict__ dst_orders,
               const int* __restrict__ src_rev,
               const int* __restrict__ dst_rev,
               const float* __restrict__ W1,
               const float* __restrict__ b1,
               const float* __restrict__ W2,
               const float* __restrict__ b2,
               const float* __restrict__ W3,
               const float* __restrict__ b3,
               float* __restrict__ out, int E)
{
    __shared__ __align__(16) float efw_lds[4][16][128];
    const int tid = threadIdx.x, wave = tid >> 6, lane = tid & 63;
    const int g = lane >> 4, e16 = lane & 15;
    float (*my_lds)[128] = efw_lds[wave];
    const int swz = (e16 & 7) << 2;

    // A frags for ef GEMM: W1c^T tiles; K-slot 16 carries b1 (B supplies 1.0)
    bfrag a1[8];
    #pragma unroll
    for (int t = 0; t < 8; ++t) {
        bfrag v;
        #pragma unroll
        for (int i = 0; i < 8; ++i) {
            const int k = g * 8 + i;
            short s16 = 0;
            if (k < 16)       s16 = f2bf(W1[(size_t)(256 + k) * 128 + t * 16 + e16]);
            else if (k == 16) s16 = f2bf(b1[t * 16 + e16]);
            v[i] = s16;
        }
        a1[t] = v;
    }
    // W2^T A-frags for the second GEMM
    bfrag w2t[2][4];
    #pragma unroll
    for (int nt = 0; nt < 2; ++nt)
        #pragma unroll
        for (int kk = 0; kk < 4; ++kk) {
            bfrag v;
            #pragma unroll
            for (int i = 0; i < 8; ++i) {
                int k = kk * 32 + g * 8 + i;
                v[i] = f2bf(W2[(size_t)k * 32 + nt * 16 + e16]);
            }
            w2t[nt][kk] = v;
        }
    float b2v[2][4], w3v[2][4];
    #pragma unroll
    for (int nt = 0; nt < 2; ++nt)
        #pragma unroll
        for (int r = 0; r < 4; ++r) {
            b2v[nt][r] = b2[nt * 16 + g * 4 + r];
            w3v[nt][r] = W3[nt * 16 + g * 4 + r];
        }
    const float b3s = b3[0];

    const long twoE = 2L * E;
    const int nbatch = (int)((twoE + 15) >> 4);
    const int stride = gridDim.x * 4;
    const int b0 = blockIdx.x * 4 + wave;

    int sn = 0, dn = 0;
    float4 ef0 = make_float4(0, 0, 0, 0), ef1 = make_float4(0, 0, 0, 0);
    uint4 ys[4], yd[4];

    auto load_idx = [&](int bb, int& S, int& D) {
        long el = ((long)bb << 4) + e16;
        if (el >= twoE) el = twoE - 1;
        const bool rv = el >= E;
        const int ee = (int)(rv ? el - E : el);
        S = (rv ? src_rev : src_orders)[ee];
        D = (rv ? dst_rev : dst_orders)[ee];
    };
    auto issue_gather = [&](int bb, int S, int D) {
        long el = ((long)bb << 4) + e16;
        if (el >= twoE) el = twoE - 1;
        const bool rv = el >= E;
        const int ee = (int)(rv ? el - E : el);
        const unsigned short* Ysp = rv ? Yi : Yu;
        const unsigned short* Ydp = rv ? Yu : Yi;
        const float* efp = rv ? ef_rev : ef_orders;
        #pragma unroll
        for (int kk = 0; kk < 4; ++kk) {
            ys[kk] = *(const uint4*)(Ysp + (size_t)S * 256 + kk * 32 + g * 8);
            yd[kk] = *(const uint4*)(Ydp + (size_t)D * 256 + 128 + kk * 32 + g * 8);
        }
        if (g < 2) {
            const float* ep = efp + (size_t)ee * 16 + g * 8;
            ef0 = *(const float4*)ep;
            ef1 = *(const float4*)(ep + 4);
        }
    };

    if (b0 < nbatch) {
        load_idx(b0, sn, dn);
        issue_gather(b0, sn, dn);
        if (b0 + stride < nbatch) load_idx(b0 + stride, sn, dn);
    }

    for (int b = b0; b < nbatch; b += stride) {
        const int bn = b + stride;

        // build B frag from prefetched ef (lanes g<2); bias-one at K=16 (g==2)
        bfrag eb;
        #pragma unroll
        for (int i = 0; i < 8; ++i) eb[i] = 0;
        if (g < 2) {
            eb[0] = f2bf(ef0.x); eb[1] = f2bf(ef0.y); eb[2] = f2bf(ef0.z); eb[3] = f2bf(ef0.w);
            eb[4] = f2bf(ef1.x); eb[5] = f2bf(ef1.y); eb[6] = f2bf(ef1.z); eb[7] = f2bf(ef1.w);
        } else if (g == 2) {
            eb[0] = (short)0x3F80;  // bf16 1.0 -> adds b1[n] to every column
        }

        // D1 = W1c^T @ ef^T + b1 -> LDS transpose (swizzled)
        #pragma unroll
        for (int t = 0; t < 8; ++t) {
            facc zero = {0, 0, 0, 0};
            facc d1 = __builtin_amdgcn_mfma_f32_16x16x32_bf16(a1[t], eb, zero, 0, 0, 0);
            *(facc*)&my_lds[e16][(t * 16 + g * 4) ^ swz] = d1;
        }

        // P build + second GEMM (consumes prefetched ys/yd)
        facc acc2[2] = {{0,0,0,0},{0,0,0,0}};
        #pragma unroll
        for (int kk = 0; kk < 4; ++kk) {
            const int k0 = kk * 32 + g * 8;
            const uint4 ysu = ys[kk], ydu = yd[kk];
            float4 w0 = *(const float4*)&my_lds[e16][k0 ^ swz];
            float4 w1 = *(const float4*)&my_lds[e16][(k0 + 4) ^ swz];
            float p0 = bf2f_lo(ysu.x) + bf2f_lo(ydu.x) + w0.x;
            float p1 = bf2f_hi(ysu.x) + bf2f_hi(ydu.x) + w0.y;
            float p2 = bf2f_lo(ysu.y) + bf2f_lo(ydu.y) + w0.z;
            float p3 = bf2f_hi(ysu.y) + bf2f_hi(ydu.y) + w0.w;
            float p4 = bf2f_lo(ysu.z) + bf2f_lo(ydu.z) + w1.x;
            float p5 = bf2f_hi(ysu.z) + bf2f_hi(ydu.z) + w1.y;
            float p6 = bf2f_lo(ysu.w) + bf2f_lo(ydu.w) + w1.z;
            float p7 = bf2f_hi(ysu.w) + bf2f_hi(ydu.w) + w1.w;
            bfrag pa;
            pa[0] = f2bf(fmaxf(p0, 0.f)); pa[1] = f2bf(fmaxf(p1, 0.f));
            pa[2] = f2bf(fmaxf(p2, 0.f)); pa[3] = f2bf(fmaxf(p3, 0.f));
            pa[4] = f2bf(fmaxf(p4, 0.f)); pa[5] = f2bf(fmaxf(p5, 0.f));
            pa[6] = f2bf(fmaxf(p6, 0.f)); pa[7] = f2bf(fmaxf(p7, 0.f));
            acc2[0] = __builtin_amdgcn_mfma_f32_16x16x32_bf16(w2t[0][kk], pa, acc2[0], 0, 0, 0);
            acc2[1] = __builtin_amdgcn_mfma_f32_16x16x32_bf16(w2t[1][kk], pa, acc2[1], 0, 0, 0);
        }

        // prefetch next batch's Y/ef (ys/yd free now; latency hides under tail
        // + next iter's D1 phase)
        if (bn < nbatch) issue_gather(bn, sn, dn);

        // tail: relu(h2+b2) . W3, reduce over g-groups, sigmoid, store
        float h3 = 0.f;
        #pragma unroll
        for (int nt = 0; nt < 2; ++nt)
            #pragma unroll
            for (int r = 0; r < 4; ++r) {
                float h2 = fmaxf(acc2[nt][r] + b2v[nt][r], 0.f);
                h3 = fmaf(h2, w3v[nt][r], h3);
            }
        h3 += __shfl_xor(h3, 16, 64);
        h3 += __shfl_xor(h3, 32, 64);
        const long el = ((long)b << 4) + lane;
        if (lane < 16 && el < twoE)
            out[el] = 1.f / (1.f + __expf(-(h3 + b3s)));

        // indices for b + 2*stride (consumed by next iteration's gather)
        const int b2n = b + 2 * stride;
        if (b2n < nbatch) load_idx(b2n, sn, dn);
    }
}

// ---------------------------------------------------------------------------
// Fallback (ws too small): direct per-edge MLP (round-1 kernel, known good).
// ---------------------------------------------------------------------------
extern "C" __global__ __launch_bounds__(256)
void edge_mlp_direct(const float* __restrict__ h_user,
                     const float* __restrict__ h_item,
                     const float* __restrict__ ef_orders,
                     const float* __restrict__ ef_rev,
                     const int* __restrict__ src_orders,
                     const int* __restrict__ dst_orders,
                     const int* __restrict__ src_rev,
                     const int* __restrict__ dst_rev,
                     const float* __restrict__ W1,
                     const float* __restrict__ b1,
                     const float* __restrict__ W2,
                     const float* __restrict__ b2,
                     const float* __restrict__ W3,
                     const float* __restrict__ b3,
                     float* __restrict__ out, int E)
{
    __shared__ unsigned short W1s[256][128];
    __shared__ float xbuf[4][256];
    __shared__ float h1s[4][128];
    const int tid = threadIdx.x;
    const int wave = tid >> 6, lane = tid & 63;
    const int f0 = 2 * lane;
    const int j2 = lane & 31;
    const int kb = (lane >> 5) * 64;

    for (int i = tid; i < 256 * 128; i += 256)
        W1s[i >> 7][i & 127] = (unsigned short)f2bf(W1[i]);
    __syncthreads();

    float w1c0[16], w1c1[16];
    #pragma unroll
    for (int k = 0; k < 16; ++k) {
        w1c0[k] = W1[(256 + k) * 128 + f0];
        w1c1[k] = W1[(256 + k) * 128 + f0 + 1];
    }
    float w2r[64];
    #pragma unroll
    for (int kk = 0; kk < 64; ++kk)
        w2r[kk] = W2[(kb + kk) * 32 + j2];
    const float b10 = b1[f0], b11 = b1[f0 + 1];
    const float b2vv = b2[j2], w3vv = W3[j2], b3v = b3[0];

    const long twoE = 2L * E;
    for (long e = (long)blockIdx.x * 4 + wave; e < twoE; e += (long)gridDim.x * 4) {
        const bool rv = (e >= E);
        const int ee = (int)(rv ? e - E : e);
        const int s = (rv ? src_rev : src_orders)[ee];
        const int d = (rv ? dst_rev : dst_orders)[ee];
        const float* hs = rv ? h_item : h_user;
        const float* hd = rv ? h_user : h_item;
        const float* efp = rv ? ef_rev : ef_orders;

        xbuf[wave][lane]       = hs[(size_t)s * 128 + lane];
        xbuf[wave][64 + lane]  = hs[(size_t)s * 128 + 64 + lane];
        xbuf[wave][128 + lane] = hd[(size_t)d * 128 + lane];
        xbuf[wave][192 + lane] = hd[(size_t)d * 128 + 64 + lane];
        __builtin_amdgcn_wave_barrier();

        float p0 = b10, p1 = b11;
        #pragma unroll 8
        for (int k = 0; k < 256; ++k) {
            float xv = xbuf[wave][k];
            unsigned int w = *(const unsigned int*)&W1s[k][f0];
            p0 = fmaf(xv, bf2f_lo(w), p0);
            p1 = fmaf(xv, bf2f_hi(w), p1);
        }
        const float efv = efp[(size_t)ee * 16 + (lane & 15)];
        #pragma unroll
        for (int k = 0; k < 16; ++k) {
            float ek = __shfl(efv, k, 64);
            p0 = fmaf(ek, w1c0[k], p0);
            p1 = fmaf(ek, w1c1[k], p1);
        }
        p0 = fmaxf(p0, 0.0f);
        p1 = fmaxf(p1, 0.0f);

        *(float2*)&h1s[wave][f0] = make_float2(p0, p1);
        __builtin_amdgcn_wave_barrier();
        float acc = 0.0f;
        #pragma unroll
        for (int q = 0; q < 16; ++q) {
            float4 hv = *(const float4*)&h1s[wave][kb + q * 4];
            acc = fmaf(hv.x, w2r[4 * q + 0], acc);
            acc = fmaf(hv.y, w2r[4 * q + 1], acc);
            acc = fmaf(hv.z, w2r[4 * q + 2], acc);
            acc = fmaf(hv.w, w2r[4 * q + 3], acc);
        }
        __builtin_amdgcn_wave_barrier();
        acc += __shfl_xor(acc, 32, 64);
        float h2 = fmaxf(acc + b2vv, 0.0f);
        float v = h2 * w3vv;
        v += __shfl_xor(v, 16, 64);
        v += __shfl_xor(v, 8, 64);
        v += __shfl_xor(v, 4, 64);
        v += __shfl_xor(v, 2, 64);
        v += __shfl_xor(v, 1, 64);
        if (lane == 0)
            out[e] = 1.0f / (1.0f + __expf(-(v + b3v)));
    }
}

// ---------------------------------------------------------------------------
extern "C" void kernel_launch(void* const* d_in, const int* in_sizes, int n_in,
                              void* d_out, int out_size, void* d_ws, size_t ws_size,
                              hipStream_t stream)
{
    const float* h_user    = (const float*)d_in[0];
    const float* h_item    = (const float*)d_in[1];
    const float* ef_orders = (const float*)d_in[2];
    const float* ef_rev    = (const float*)d_in[3];
    const float* W1        = (const float*)d_in[4];
    const float* b1        = (const float*)d_in[5];
    const float* W2        = (const float*)d_in[6];
    const float* b2        = (const float*)d_in[7];
    const float* W3        = (const float*)d_in[8];
    const float* b3        = (const float*)d_in[9];
    const int* src_orders  = (const int*)d_in[10];
    const int* dst_orders  = (const int*)d_in[11];
    const int* src_rev     = (const int*)d_in[12];
    const int* dst_rev     = (const int*)d_in[13];

    const int n_user = in_sizes[0] / 128;
    const int n_item = in_sizes[1] / 128;
    const int E      = in_sizes[2] / 16;
    float* out = (float*)d_out;

    const size_t need = (size_t)(n_user + n_item) * 256 * sizeof(unsigned short);
    if (ws_size >= need) {
        unsigned short* Yu = (unsigned short*)d_ws;
        unsigned short* Yi = Yu + (size_t)n_user * 256;
        precompute_mfma<<<2048, 256, 0, stream>>>(h_user, n_user, h_item, n_item, W1, Yu, Yi);
        edge_mfma<<<2048, 256, 0, stream>>>(Yu, Yi, ef_orders, ef_rev,
            src_orders, dst_orders, src_rev, dst_rev,
            W1, b1, W2, b2, W3, b3, out, E);
    } else {
        edge_mlp_direct<<<4096, 256, 0, stream>>>(h_user, h_item, ef_orders, ef_rev,
            src_orders, dst_orders, src_rev, dst_rev,
            W1, b1, W2, b2, W3, b3, out, E);
    }
}

// Round 4
// 212.562 us; speedup vs baseline: 3.2121x; 1.1674x over previous
//
#include <hip/hip_runtime.h>
#include <hip/hip_bf16.h>

typedef __attribute__((ext_vector_type(8))) short bfrag;   // 8 bf16 (A/B operand)
typedef __attribute__((ext_vector_type(4))) float facc;    // 4 f32  (C/D operand)

static __device__ __forceinline__ float bf2f_lo(unsigned int u) {
    return __uint_as_float(u << 16);
}
static __device__ __forceinline__ float bf2f_hi(unsigned int u) {
    return __uint_as_float(u & 0xffff0000u);
}
static __device__ __forceinline__ unsigned short f2bf(float f) {
    __hip_bfloat16 b = __float2bfloat16(f);  // RNE
    return *reinterpret_cast<unsigned short*>(&b);
}

// ---------------------------------------------------------------------------
// Merged precompute: Y[row][0:128] = h@W1[0:128], Y[row][128:256] = h@W1[128:256]
// for BOTH node tables in one launch (grid-stride over user tiles then item).
// MFMA 16x16x32 bf16; wave w owns cols [w*64, w*64+64); W1 frags in registers.
// D layout (verified): col = lane&15, row = (lane>>4)*4 + reg.
// ---------------------------------------------------------------------------
extern "C" __global__ __launch_bounds__(256)
void precompute_mfma(const float* __restrict__ hu, int nu,
                     const float* __restrict__ hi, int ni,
                     const float* __restrict__ W1,
                     unsigned short* __restrict__ Yu,
                     unsigned short* __restrict__ Yi)
{
    const int tid = threadIdx.x, wave = tid >> 6, lane = tid & 63;
    const int g = lane >> 4, e16 = lane & 15;
    const int c0 = wave * 64;

    bfrag bfr[4][4];
    #pragma unroll
    for (int nt = 0; nt < 4; ++nt) {
        const int j = c0 + nt * 16 + e16;
        #pragma unroll
        for (int kk = 0; kk < 4; ++kk) {
            bfrag v;
            #pragma unroll
            for (int i = 0; i < 8; ++i) {
                int k = kk * 32 + g * 8 + i;
                float w = (j < 128) ? W1[(size_t)k * 128 + j]
                                    : W1[(size_t)(128 + k) * 128 + (j - 128)];
                v[i] = (short)f2bf(w);
            }
            bfr[nt][kk] = v;
        }
    }

    const int tu = (nu + 15) >> 4, ti = (ni + 15) >> 4, tt = tu + ti;
    for (int tile = blockIdx.x; tile < tt; tile += gridDim.x) {
        const float* h; unsigned short* Y; int n, node0;
        if (tile < tu) { h = hu; Y = Yu; n = nu; node0 = tile * 16; }
        else           { h = hi; Y = Yi; n = ni; node0 = (tile - tu) * 16; }

        int arow = node0 + e16; if (arow >= n) arow = n - 1;
        facc acc[4] = {{0,0,0,0},{0,0,0,0},{0,0,0,0},{0,0,0,0}};
        #pragma unroll
        for (int kk = 0; kk < 4; ++kk) {
            const float* ap = h + (size_t)arow * 128 + kk * 32 + g * 8;
            float4 a0 = *(const float4*)ap;
            float4 a1v = *(const float4*)(ap + 4);
            bfrag af;
            af[0] = (short)f2bf(a0.x);  af[1] = (short)f2bf(a0.y);
            af[2] = (short)f2bf(a0.z);  af[3] = (short)f2bf(a0.w);
            af[4] = (short)f2bf(a1v.x); af[5] = (short)f2bf(a1v.y);
            af[6] = (short)f2bf(a1v.z); af[7] = (short)f2bf(a1v.w);
            #pragma unroll
            for (int nt = 0; nt < 4; ++nt)
                acc[nt] = __builtin_amdgcn_mfma_f32_16x16x32_bf16(af, bfr[nt][kk], acc[nt], 0, 0, 0);
        }
        #pragma unroll
        for (int nt = 0; nt < 4; ++nt)
            #pragma unroll
            for (int r = 0; r < 4; ++r) {
                int row = node0 + g * 4 + r;
                if (row < n)
                    Y[(size_t)row * 256 + c0 + nt * 16 + e16] = f2bf(acc[nt][r]);
            }
    }
}

// ---------------------------------------------------------------------------
// Edge phase: 16 edges/wave/iter, edges-as-columns MFMA, software-pipelined.
// Round-4 fix: prefetch state in NAMED uint4 registers (no arrays, no lambdas
// -> no address-taken -> no scratch spill). D1 transpose buffer is bf16
// (16 KB/block), XOR-swizzled at 16B granule.
// ---------------------------------------------------------------------------
extern "C" __global__ __launch_bounds__(256, 3)
void edge_mfma(const unsigned short* __restrict__ Yu,
               const unsigned short* __restrict__ Yi,
               const float* __restrict__ ef_orders,
               const float* __restrict__ ef_rev,
               const int* __restrict__ src_orders,
               const int* __restrict__ dst_orders,
               const int* __restrict__ src_rev,
               const int* __restrict__ dst_rev,
               const float* __restrict__ W1,
               const float* __restrict__ b1,
               const float* __restrict__ W2,
               const float* __restrict__ b2,
               const float* __restrict__ W3,
               const float* __restrict__ b3,
               float* __restrict__ out, int E)
{
    __shared__ __align__(16) unsigned short d1_lds[4][16][128];  // 16 KB
    const int tid = threadIdx.x, wave = tid >> 6, lane = tid & 63;
    const int g = lane >> 4, e16 = lane & 15;
    unsigned short (*my_lds)[128] = d1_lds[wave];
    const int swzb = (e16 & 7) << 3;   // bf16-unit XOR, 16B granule

    // A frags for ef GEMM: W1c^T tiles; K-slot 16 carries b1 (B supplies 1.0)
    bfrag a1[8];
    #pragma unroll
    for (int t = 0; t < 8; ++t) {
        bfrag v;
        #pragma unroll
        for (int i = 0; i < 8; ++i) {
            const int k = g * 8 + i;
            unsigned short s16 = 0;
            if (k < 16)       s16 = f2bf(W1[(size_t)(256 + k) * 128 + t * 16 + e16]);
            else if (k == 16) s16 = f2bf(b1[t * 16 + e16]);
            v[i] = (short)s16;
        }
        a1[t] = v;
    }
    // W2^T A-frags for the second GEMM
    bfrag w2t[2][4];
    #pragma unroll
    for (int nt = 0; nt < 2; ++nt)
        #pragma unroll
        for (int kk = 0; kk < 4; ++kk) {
            bfrag v;
            #pragma unroll
            for (int i = 0; i < 8; ++i) {
                int k = kk * 32 + g * 8 + i;
                v[i] = (short)f2bf(W2[(size_t)k * 32 + nt * 16 + e16]);
            }
            w2t[nt][kk] = v;
        }
    float b2v[2][4], w3v[2][4];
    #pragma unroll
    for (int nt = 0; nt < 2; ++nt)
        #pragma unroll
        for (int r = 0; r < 4; ++r) {
            b2v[nt][r] = b2[nt * 16 + g * 4 + r];
            w3v[nt][r] = W3[nt * 16 + g * 4 + r];
        }
    const float b3s = b3[0];

    const long twoE = 2L * E;
    const int nbatch = (int)((twoE + 15) >> 4);
    const int stride = gridDim.x * 4;
    int b = blockIdx.x * 4 + wave;

    // pipeline state — all named scalars/vectors (register-resident)
    int s_pf = 0, d_pf = 0;
    uint4 ys0, ys1, ys2, ys3, yd0, yd1, yd2, yd3;
    float4 ef0 = make_float4(0, 0, 0, 0), ef1 = make_float4(0, 0, 0, 0);

#define LOADIDX(BB) do {                                                      \
        long el_ = ((long)(BB) << 4) + e16;                                   \
        if (el_ >= twoE) el_ = twoE - 1;                                      \
        const bool rv_ = el_ >= E;                                            \
        const int ee_ = (int)(rv_ ? el_ - E : el_);                           \
        s_pf = (rv_ ? src_rev : src_orders)[ee_];                             \
        d_pf = (rv_ ? dst_rev : dst_orders)[ee_];                             \
    } while (0)

#define GATHER(BB) do {                                                       \
        long el_ = ((long)(BB) << 4) + e16;                                   \
        if (el_ >= twoE) el_ = twoE - 1;                                      \
        const bool rv_ = el_ >= E;                                            \
        const int ee_ = (int)(rv_ ? el_ - E : el_);                           \
        const unsigned short* ps_ = (rv_ ? Yi : Yu) + (size_t)s_pf * 256 + g * 8; \
        const unsigned short* pd_ = (rv_ ? Yu : Yi) + (size_t)d_pf * 256 + 128 + g * 8; \
        ys0 = *(const uint4*)(ps_);      ys1 = *(const uint4*)(ps_ + 32);     \
        ys2 = *(const uint4*)(ps_ + 64); ys3 = *(const uint4*)(ps_ + 96);     \
        yd0 = *(const uint4*)(pd_);      yd1 = *(const uint4*)(pd_ + 32);     \
        yd2 = *(const uint4*)(pd_ + 64); yd3 = *(const uint4*)(pd_ + 96);     \
        if (g < 2) {                                                          \
            const float* ep_ = (rv_ ? ef_rev : ef_orders) + (size_t)ee_ * 16 + g * 8; \
            ef0 = *(const float4*)ep_;  ef1 = *(const float4*)(ep_ + 4);      \
        }                                                                     \
    } while (0)

#define PSTEP(KK, YSU, YDU) do {                                              \
        uint4 wv = *(const uint4*)&my_lds[e16][((KK) * 32 + g * 8) ^ swzb];   \
        float p0 = bf2f_lo(YSU.x) + bf2f_lo(YDU.x) + bf2f_lo(wv.x);           \
        float p1 = bf2f_hi(YSU.x) + bf2f_hi(YDU.x) + bf2f_hi(wv.x);           \
        float p2 = bf2f_lo(YSU.y) + bf2f_lo(YDU.y) + bf2f_lo(wv.y);           \
        float p3 = bf2f_hi(YSU.y) + bf2f_hi(YDU.y) + bf2f_hi(wv.y);           \
        float p4 = bf2f_lo(YSU.z) + bf2f_lo(YDU.z) + bf2f_lo(wv.z);           \
        float p5 = bf2f_hi(YSU.z) + bf2f_hi(YDU.z) + bf2f_hi(wv.z);           \
        float p6 = bf2f_lo(YSU.w) + bf2f_lo(YDU.w) + bf2f_lo(wv.w);           \
        float p7 = bf2f_hi(YSU.w) + bf2f_hi(YDU.w) + bf2f_hi(wv.w);           \
        bfrag pa;                                                             \
        pa[0] = (short)f2bf(fmaxf(p0, 0.f)); pa[1] = (short)f2bf(fmaxf(p1, 0.f)); \
        pa[2] = (short)f2bf(fmaxf(p2, 0.f)); pa[3] = (short)f2bf(fmaxf(p3, 0.f)); \
        pa[4] = (short)f2bf(fmaxf(p4, 0.f)); pa[5] = (short)f2bf(fmaxf(p5, 0.f)); \
        pa[6] = (short)f2bf(fmaxf(p6, 0.f)); pa[7] = (short)f2bf(fmaxf(p7, 0.f)); \
        acc2a = __builtin_amdgcn_mfma_f32_16x16x32_bf16(w2t[0][KK], pa, acc2a, 0, 0, 0); \
        acc2b = __builtin_amdgcn_mfma_f32_16x16x32_bf16(w2t[1][KK], pa, acc2b, 0, 0, 0); \
    } while (0)

    if (b < nbatch) {
        LOADIDX(b);
        GATHER(b);
        if (b + stride < nbatch) LOADIDX(b + stride);
    }

    for (; b < nbatch; b += stride) {
        // B frag from prefetched ef (lanes g<2); bias-one at K=16 (g==2)
        bfrag eb;
        #pragma unroll
        for (int i = 0; i < 8; ++i) eb[i] = 0;
        if (g < 2) {
            eb[0] = (short)f2bf(ef0.x); eb[1] = (short)f2bf(ef0.y);
            eb[2] = (short)f2bf(ef0.z); eb[3] = (short)f2bf(ef0.w);
            eb[4] = (short)f2bf(ef1.x); eb[5] = (short)f2bf(ef1.y);
            eb[6] = (short)f2bf(ef1.z); eb[7] = (short)f2bf(ef1.w);
        } else if (g == 2) {
            eb[0] = (short)0x3F80;  // bf16 1.0 -> adds b1[n] to every column
        }

        // D1 = W1c^T @ ef^T + b1 -> bf16 LDS transpose (swizzled)
        #pragma unroll
        for (int t = 0; t < 8; ++t) {
            facc zero = {0, 0, 0, 0};
            facc d1 = __builtin_amdgcn_mfma_f32_16x16x32_bf16(a1[t], eb, zero, 0, 0, 0);
            ushort4 u;
            u.x = f2bf(d1[0]); u.y = f2bf(d1[1]); u.z = f2bf(d1[2]); u.w = f2bf(d1[3]);
            *(ushort4*)&my_lds[e16][(t * 16 + g * 4) ^ swzb] = u;
        }

        // P build + second GEMM (consumes prefetched ys/yd registers)
        facc acc2a = {0, 0, 0, 0}, acc2b = {0, 0, 0, 0};
        PSTEP(0, ys0, yd0);
        PSTEP(1, ys1, yd1);
        PSTEP(2, ys2, yd2);
        PSTEP(3, ys3, yd3);

        // issue next batch's gathers now that ys/yd are consumed;
        // latency hides under tail + next iter's D1 phase (+ 3 waves/SIMD TLP)
        const int bn = b + stride;
        if (bn < nbatch) GATHER(bn);

        // tail: relu(h2+b2) . W3, reduce over g-groups, sigmoid, store
        float h3 = 0.f;
        #pragma unroll
        for (int r = 0; r < 4; ++r) {
            float h2 = fmaxf(acc2a[r] + b2v[0][r], 0.f);
            h3 = fmaf(h2, w3v[0][r], h3);
        }
        #pragma unroll
        for (int r = 0; r < 4; ++r) {
            float h2 = fmaxf(acc2b[r] + b2v[1][r], 0.f);
            h3 = fmaf(h2, w3v[1][r], h3);
        }
        h3 += __shfl_xor(h3, 16, 64);
        h3 += __shfl_xor(h3, 32, 64);
        const long el = ((long)b << 4) + lane;
        if (lane < 16 && el < twoE)
            out[el] = 1.f / (1.f + __expf(-(h3 + b3s)));

        // indices for b + 2*stride (consumed by next iteration's GATHER)
        const int b2n = b + 2 * stride;
        if (b2n < nbatch) LOADIDX(b2n);
    }
#undef LOADIDX
#undef GATHER
#undef PSTEP
}

// ---------------------------------------------------------------------------
// Fallback (ws too small): direct per-edge MLP (round-1 kernel, known good).
// ---------------------------------------------------------------------------
extern "C" __global__ __launch_bounds__(256)
void edge_mlp_direct(const float* __restrict__ h_user,
                     const float* __restrict__ h_item,
                     const float* __restrict__ ef_orders,
                     const float* __restrict__ ef_rev,
                     const int* __restrict__ src_orders,
                     const int* __restrict__ dst_orders,
                     const int* __restrict__ src_rev,
                     const int* __restrict__ dst_rev,
                     const float* __restrict__ W1,
                     const float* __restrict__ b1,
                     const float* __restrict__ W2,
                     const float* __restrict__ b2,
                     const float* __restrict__ W3,
                     const float* __restrict__ b3,
                     float* __restrict__ out, int E)
{
    __shared__ unsigned short W1s[256][128];
    __shared__ float xbuf[4][256];
    __shared__ float h1s[4][128];
    const int tid = threadIdx.x;
    const int wave = tid >> 6, lane = tid & 63;
    const int f0 = 2 * lane;
    const int j2 = lane & 31;
    const int kb = (lane >> 5) * 64;

    for (int i = tid; i < 256 * 128; i += 256)
        W1s[i >> 7][i & 127] = f2bf(W1[i]);
    __syncthreads();

    float w1c0[16], w1c1[16];
    #pragma unroll
    for (int k = 0; k < 16; ++k) {
        w1c0[k] = W1[(256 + k) * 128 + f0];
        w1c1[k] = W1[(256 + k) * 128 + f0 + 1];
    }
    float w2r[64];
    #pragma unroll
    for (int kk = 0; kk < 64; ++kk)
        w2r[kk] = W2[(kb + kk) * 32 + j2];
    const float b10 = b1[f0], b11 = b1[f0 + 1];
    const float b2vv = b2[j2], w3vv = W3[j2], b3v = b3[0];

    const long twoE = 2L * E;
    for (long e = (long)blockIdx.x * 4 + wave; e < twoE; e += (long)gridDim.x * 4) {
        const bool rv = (e >= E);
        const int ee = (int)(rv ? e - E : e);
        const int s = (rv ? src_rev : src_orders)[ee];
        const int d = (rv ? dst_rev : dst_orders)[ee];
        const float* hs = rv ? h_item : h_user;
        const float* hd = rv ? h_user : h_item;
        const float* efp = rv ? ef_rev : ef_orders;

        xbuf[wave][lane]       = hs[(size_t)s * 128 + lane];
        xbuf[wave][64 + lane]  = hs[(size_t)s * 128 + 64 + lane];
        xbuf[wave][128 + lane] = hd[(size_t)d * 128 + lane];
        xbuf[wave][192 + lane] = hd[(size_t)d * 128 + 64 + lane];
        __builtin_amdgcn_wave_barrier();

        float p0 = b10, p1 = b11;
        #pragma unroll 8
        for (int k = 0; k < 256; ++k) {
            float xv = xbuf[wave][k];
            unsigned int w = *(const unsigned int*)&W1s[k][f0];
            p0 = fmaf(xv, bf2f_lo(w), p0);
            p1 = fmaf(xv, bf2f_hi(w), p1);
        }
        const float efv = efp[(size_t)ee * 16 + (lane & 15)];
        #pragma unroll
        for (int k = 0; k < 16; ++k) {
            float ek = __shfl(efv, k, 64);
            p0 = fmaf(ek, w1c0[k], p0);
            p1 = fmaf(ek, w1c1[k], p1);
        }
        p0 = fmaxf(p0, 0.0f);
        p1 = fmaxf(p1, 0.0f);

        *(float2*)&h1s[wave][f0] = make_float2(p0, p1);
        __builtin_amdgcn_wave_barrier();
        float acc = 0.0f;
        #pragma unroll
        for (int q = 0; q < 16; ++q) {
            float4 hv = *(const float4*)&h1s[wave][kb + q * 4];
            acc = fmaf(hv.x, w2r[4 * q + 0], acc);
            acc = fmaf(hv.y, w2r[4 * q + 1], acc);
            acc = fmaf(hv.z, w2r[4 * q + 2], acc);
            acc = fmaf(hv.w, w2r[4 * q + 3], acc);
        }
        __builtin_amdgcn_wave_barrier();
        acc += __shfl_xor(acc, 32, 64);
        float h2 = fmaxf(acc + b2vv, 0.0f);
        float v = h2 * w3vv;
        v += __shfl_xor(v, 16, 64);
        v += __shfl_xor(v, 8, 64);
        v += __shfl_xor(v, 4, 64);
        v += __shfl_xor(v, 2, 64);
        v += __shfl_xor(v, 1, 64);
        if (lane == 0)
            out[e] = 1.0f / (1.0f + __expf(-(v + b3v)));
    }
}

// ---------------------------------------------------------------------------
extern "C" void kernel_launch(void* const* d_in, const int* in_sizes, int n_in,
                              void* d_out, int out_size, void* d_ws, size_t ws_size,
                              hipStream_t stream)
{
    const float* h_user    = (const float*)d_in[0];
    const float* h_item    = (const float*)d_in[1];
    const float* ef_orders = (const float*)d_in[2];
    const float* ef_rev    = (const float*)d_in[3];
    const float* W1        = (const float*)d_in[4];
    const float* b1        = (const float*)d_in[5];
    const float* W2        = (const float*)d_in[6];
    const float* b2        = (const float*)d_in[7];
    const float* W3        = (const float*)d_in[8];
    const float* b3        = (const float*)d_in[9];
    const int* src_orders  = (const int*)d_in[10];
    const int* dst_orders  = (const int*)d_in[11];
    const int* src_rev     = (const int*)d_in[12];
    const int* dst_rev     = (const int*)d_in[13];

    const int n_user = in_sizes[0] / 128;
    const int n_item = in_sizes[1] / 128;
    const int E      = in_sizes[2] / 16;
    float* out = (float*)d_out;

    const size_t need = (size_t)(n_user + n_item) * 256 * sizeof(unsigned short);
    if (ws_size >= need) {
        unsigned short* Yu = (unsigned short*)d_ws;
        unsigned short* Yi = Yu + (size_t)n_user * 256;
        precompute_mfma<<<2048, 256, 0, stream>>>(h_user, n_user, h_item, n_item, W1, Yu, Yi);
        edge_mfma<<<1024, 256, 0, stream>>>(Yu, Yi, ef_orders, ef_rev,
            src_orders, dst_orders, src_rev, dst_rev,
            W1, b1, W2, b2, W3, b3, out, E);
    } else {
        edge_mlp_direct<<<4096, 256, 0, stream>>>(h_user, h_item, ef_orders, ef_rev,
            src_orders, dst_orders, src_rev, dst_rev,
            W1, b1, W2, b2, W3, b3, out, E);
    }
}